// Round 4
// baseline (227.232 us; speedup 1.0000x reference)
//
#include <hip/hip_runtime.h>
#include <cstdint>

#define VOCAB 100000
#define NB    2048
#define SEQ   50
#define HID   256
#define XIN   512
#define NE    64
#define NP    5

#define BEO_BLOCKS 256
#define BEO_ROWS   8
#define NBLK (BEO_BLOCKS + NB)

#define OFF_BOW_E 0
#define OFF_BEO_E (NB*NE)
#define OFF_BOW_P (2*NB*NE)
#define OFF_BEO_P (2*NB*NE + NB*NP)

#define GITER 13            // tokens per wave: i = w + 4*ii, covers 0..51 (50..51 pad)

struct BeoS { float xs[BEO_ROWS][XIN]; };                 // 16 KB (hs reuses this)
struct BowS { float part[4*HID]; float h[HID]; };          // 5 KB
union  SMem { BeoS beo; BowS bow; };

__global__ __launch_bounds__(256, 1) void fused_kernel(
    const int*   __restrict__ s,   const float* __restrict__ x,
    const float* __restrict__ Wbh, const float* __restrict__ bbh,
    const float* __restrict__ Wbp, const float* __restrict__ bbp,
    const float* __restrict__ Wbe, const float* __restrict__ bbe,
    const float* __restrict__ Weh, const float* __restrict__ beh,
    const float* __restrict__ Wep, const float* __restrict__ bep,
    const float* __restrict__ Wee, const float* __restrict__ bee,
    float* __restrict__ out)
{
    __shared__ SMem sm;
    const int tid = threadIdx.x;
    const int blk = blockIdx.x;

    if (blk < BEO_BLOCKS) {
        // ---------------- beo path: 8 batch rows per block ----------------
        const int r0 = blk * BEO_ROWS;
        {
            const float4* src = (const float4*)(x + (size_t)r0 * XIN);
            float4*       dst = (float4*)&sm.beo.xs[0][0];
            #pragma unroll
            for (int i = 0; i < (BEO_ROWS*XIN/4)/256; ++i)
                dst[i*256 + tid] = src[i*256 + tid];
        }
        __syncthreads();

        float acc[BEO_ROWS];
        {
            float bv = beh[tid];
            #pragma unroll
            for (int r = 0; r < BEO_ROWS; ++r) acc[r] = bv;
        }
        for (int k = 0; k < XIN; k += 4) {
            #pragma unroll
            for (int kk = 0; kk < 4; ++kk) {
                float w = Weh[(size_t)(k+kk)*HID + tid];   // coalesced, L2-hot
                #pragma unroll
                for (int r = 0; r < BEO_ROWS; ++r)
                    acc[r] = fmaf(sm.beo.xs[r][k+kk], w, acc[r]);
            }
        }
        __syncthreads();                       // all xs reads done
        float* hs = &sm.beo.xs[0][0];          // reuse LDS as hs[BEO_ROWS][HID]
        #pragma unroll
        for (int r = 0; r < BEO_ROWS; ++r) {
            float v = acc[r];
            hs[r*HID + tid] = v > 0.f ? v : 0.2f*v;
        }
        __syncthreads();

        // embd head: 8 rows x 64 cols -> 2 outputs per thread
        {
            const int jj = tid & 63;
            const int r  = tid >> 6;           // rows r and r+4
            float s0 = 0.f, s1 = 0.f;
            for (int k = 0; k < HID; ++k) {
                float w = Wee[k*NE + jj];
                s0 = fmaf(hs[r*HID + k],     w, s0);
                s1 = fmaf(hs[(r+4)*HID + k], w, s1);
            }
            float bias = bee[jj];
            out[OFF_BEO_E + (size_t)(r0+r)*NE   + jj] = s0 + bias;
            out[OFF_BEO_E + (size_t)(r0+r+4)*NE + jj] = s1 + bias;
        }
        // pred head: 8 rows x 5 cols
        if (tid < BEO_ROWS*NP) {
            const int r = tid / NP, jj = tid % NP;
            float sp = bep[jj];
            for (int k = 0; k < HID; ++k)
                sp = fmaf(hs[r*HID + k], Wep[k*NP + jj], sp);
            out[OFF_BEO_P + (size_t)(r0+r)*NP + jj] = sp;
        }
    } else {
        // ---------------- bow path: 1 batch row per block ----------------
        // No LDS prologue, no serial dedup: tokens read as wave-uniform
        // scalar loads; dedup via register-only ballot; all 13 row-gathers
        // issued back-to-back and PINNED by sched_barrier(0) so the
        // scheduler cannot re-serialize them (R2/R3: VGPR=52 proved it did).
        const int row  = blk - BEO_BLOCKS;
        const int lane = tid & 63;
        const int w    = tid >> 6;
        const int* srow = s + row * SEQ;

        // lane j holds token j (j<50); others hold -3 (never matches)
        int tokl = (lane < SEQ) ? srow[lane] : -3;

        int   tk[GITER];
        float mk[GITER];
        #pragma unroll
        for (int ii = 0; ii < GITER; ++ii) {
            const int i = w + 4*ii;                 // this wave's token index
            int t = (i < SEQ) ? srow[i] : -3;       // uniform addr -> s_load
            t = __builtin_amdgcn_readfirstlane(t);
            unsigned long long dup = __ballot(lane < i && tokl == t);
            mk[ii] = (t >= 0 && dup == 0ull) ? 1.0f : 0.0f;
            tk[ii] = (t < 0) ? 0 : t;
        }

        // Issue ALL 13 1KB row-gathers (lane l -> cols 4l..4l+3)
        float4 v[GITER];
        const float* wbase = Wbh + (size_t)lane * 4;
        #pragma unroll
        for (int ii = 0; ii < GITER; ++ii)
            v[ii] = *(const float4*)(wbase + (size_t)tk[ii] * HID);
        __builtin_amdgcn_sched_barrier(0);   // loads may not sink past here

        float ax = 0.f, ay = 0.f, az = 0.f, aw = 0.f;
        #pragma unroll
        for (int ii = 0; ii < GITER; ++ii) {
            ax = fmaf(mk[ii], v[ii].x, ax);
            ay = fmaf(mk[ii], v[ii].y, ay);
            az = fmaf(mk[ii], v[ii].z, az);
            aw = fmaf(mk[ii], v[ii].w, aw);
        }
        *(float4*)&sm.bow.part[w*HID + lane*4] = make_float4(ax, ay, az, aw);
        __syncthreads();
        {
            float hv = sm.bow.part[tid] + sm.bow.part[HID + tid]
                     + sm.bow.part[2*HID + tid] + sm.bow.part[3*HID + tid]
                     + bbh[tid];
            hv = hv > 0.f ? hv : 0.2f*hv;
            sm.bow.h[tid] = hv;
        }
        __syncthreads();

        // embd head: 64 outs, 4 partials each (all 4 waves busy)
        {
            const int jj = tid & 63, p = tid >> 6;
            float ps = 0.f;
            #pragma unroll 8
            for (int kk = 0; kk < 64; ++kk) {
                int k = p*64 + kk;
                ps = fmaf(sm.bow.h[k], Wbe[k*NE + jj], ps);
            }
            sm.bow.part[tid] = ps;
        }
        __syncthreads();
        // pred partials: 5 outs x 8 partials (threads 0..39), reads h only
        float pp = 0.f;
        if (tid < 8*NP) {
            const int p = tid / NP, jj = tid % NP;
            #pragma unroll 8
            for (int kk = 0; kk < 32; ++kk) {
                int k = p*32 + kk;
                pp = fmaf(sm.bow.h[k], Wbp[k*NP + jj], pp);
            }
        }
        // embd reduce (part holds embd partials here)
        if (tid < NE) {
            float e = sm.bow.part[tid] + sm.bow.part[tid+64]
                    + sm.bow.part[tid+128] + sm.bow.part[tid+192] + bbe[tid];
            out[OFF_BOW_E + (size_t)row*NE + tid] = e;
        }
        __syncthreads();
        if (tid < 8*NP) sm.bow.part[tid] = pp;
        __syncthreads();
        if (tid < NP) {
            float sp = bbp[tid];
            #pragma unroll
            for (int q = 0; q < 8; ++q) sp += sm.bow.part[q*NP + tid];
            out[OFF_BOW_P + (size_t)row*NP + tid] = sp;
        }
    }
}

extern "C" void kernel_launch(void* const* d_in, const int* in_sizes, int n_in,
                              void* d_out, int out_size, void* d_ws, size_t ws_size,
                              hipStream_t stream) {
    const int*   s   = (const int*)  d_in[0];
    const float* x   = (const float*)d_in[1];
    const float* Wbh = (const float*)d_in[2];
    const float* bbh = (const float*)d_in[3];
    const float* Wbp = (const float*)d_in[4];
    const float* bbp = (const float*)d_in[5];
    const float* Wbe = (const float*)d_in[6];
    const float* bbe = (const float*)d_in[7];
    const float* Weh = (const float*)d_in[8];
    const float* beh = (const float*)d_in[9];
    const float* Wep = (const float*)d_in[10];
    const float* bep = (const float*)d_in[11];
    const float* Wee = (const float*)d_in[12];
    const float* bee = (const float*)d_in[13];

    fused_kernel<<<dim3(NBLK), dim3(256), 0, stream>>>(
        s, x, Wbh, bbh, Wbp, bbp, Wbe, bbe,
        Weh, beh, Wep, bep, Wee, bee, (float*)d_out);
}

// Round 5
// 215.159 us; speedup vs baseline: 1.0561x; 1.0561x over previous
//
#include <hip/hip_runtime.h>
#include <cstdint>

#define VOCAB 100000
#define NB    2048
#define SEQ   50
#define HID   256
#define XIN   512
#define NE    64
#define NP    5

#define BEO_BLOCKS 256
#define BEO_ROWS   8
#define NBLK (BEO_BLOCKS + NB)

#define OFF_BOW_E 0
#define OFF_BEO_E (NB*NE)
#define OFF_BOW_P (2*NB*NE)
#define OFF_BEO_P (2*NB*NE + NB*NP)

#define GITER 13            // tokens per wave: i = w + 4*ii, covers 0..51 (50..51 pad)

struct BeoS { float xs[BEO_ROWS][XIN]; };                 // 16 KB (hs reuses this)
struct BowS { float part[4*HID]; float h[HID]; };          // 5 KB
union  SMem { BeoS beo; BowS bow; };

__global__ __launch_bounds__(256, 1) void fused_kernel(
    const int*   __restrict__ s,   const float* __restrict__ x,
    const float* __restrict__ Wbh, const float* __restrict__ bbh,
    const float* __restrict__ Wbp, const float* __restrict__ bbp,
    const float* __restrict__ Wbe, const float* __restrict__ bbe,
    const float* __restrict__ Weh, const float* __restrict__ beh,
    const float* __restrict__ Wep, const float* __restrict__ bep,
    const float* __restrict__ Wee, const float* __restrict__ bee,
    float* __restrict__ out)
{
    __shared__ SMem sm;
    const int tid = threadIdx.x;
    const int blk = blockIdx.x;

    if (blk < BEO_BLOCKS) {
        // ---------------- beo path: 8 batch rows per block ----------------
        // R1-R4 postmortem: these 256 blocks (1 per CU, no parallelism slack)
        // were the duration tail (Occupancy 27% = long 4-wave/CU phase).
        // Inner loop rewritten float4: 4 grouped Weh loads + 8 ds_read_b128
        // broadcasts + 32 fma per k4 (was 4x the LDS ops, 1-by-1 loads).
        const int r0 = blk * BEO_ROWS;
        {
            const float4* src = (const float4*)(x + (size_t)r0 * XIN);
            float4*       dst = (float4*)&sm.beo.xs[0][0];
            #pragma unroll
            for (int i = 0; i < (BEO_ROWS*XIN/4)/256; ++i)
                dst[i*256 + tid] = src[i*256 + tid];
        }
        __syncthreads();

        float acc[BEO_ROWS];
        {
            float bv = beh[tid];
            #pragma unroll
            for (int r = 0; r < BEO_ROWS; ++r) acc[r] = bv;
        }
        const float4* xs4 = (const float4*)&sm.beo.xs[0][0];   // [r*(XIN/4)+k4]
        #pragma unroll 2
        for (int k4 = 0; k4 < XIN/4; ++k4) {
            const float* wcol = Weh + (size_t)(4*k4)*HID + tid;
            float w0 = wcol[0];
            float w1 = wcol[HID];
            float w2 = wcol[2*HID];
            float w3 = wcol[3*HID];
            #pragma unroll
            for (int r = 0; r < BEO_ROWS; ++r) {
                float4 xv = xs4[r*(XIN/4) + k4];
                acc[r] = fmaf(xv.x, w0, acc[r]);
                acc[r] = fmaf(xv.y, w1, acc[r]);
                acc[r] = fmaf(xv.z, w2, acc[r]);
                acc[r] = fmaf(xv.w, w3, acc[r]);
            }
        }
        __syncthreads();                       // all xs reads done
        float* hs = &sm.beo.xs[0][0];          // reuse LDS as hs[BEO_ROWS][HID]
        #pragma unroll
        for (int r = 0; r < BEO_ROWS; ++r) {
            float v = acc[r];
            hs[r*HID + tid] = v > 0.f ? v : 0.2f*v;
        }
        __syncthreads();

        // embd head: 8 rows x 64 cols -> 2 outputs per thread (float4 form)
        {
            const int jj = tid & 63;
            const int r  = tid >> 6;           // rows r and r+4
            const float4* hs4 = (const float4*)hs;
            float s0 = 0.f, s1 = 0.f;
            #pragma unroll 4
            for (int k4 = 0; k4 < HID/4; ++k4) {
                float4 ha = hs4[r*(HID/4) + k4];
                float4 hb = hs4[(r+4)*(HID/4) + k4];
                const float* wp = Wee + (size_t)(4*k4)*NE + jj;
                float w0 = wp[0], w1 = wp[NE], w2 = wp[2*NE], w3 = wp[3*NE];
                s0 = fmaf(ha.x, w0, s0); s0 = fmaf(ha.y, w1, s0);
                s0 = fmaf(ha.z, w2, s0); s0 = fmaf(ha.w, w3, s0);
                s1 = fmaf(hb.x, w0, s1); s1 = fmaf(hb.y, w1, s1);
                s1 = fmaf(hb.z, w2, s1); s1 = fmaf(hb.w, w3, s1);
            }
            float bias = bee[jj];
            out[OFF_BEO_E + (size_t)(r0+r)*NE   + jj] = s0 + bias;
            out[OFF_BEO_E + (size_t)(r0+r+4)*NE + jj] = s1 + bias;
        }
        // pred head: 8 rows x 5 cols
        if (tid < BEO_ROWS*NP) {
            const int r = tid / NP, jj = tid % NP;
            float sp = bep[jj];
            for (int k = 0; k < HID; ++k)
                sp = fmaf(hs[r*HID + k], Wep[k*NP + jj], sp);
            out[OFF_BEO_P + (size_t)(r0+r)*NP + jj] = sp;
        }
    } else {
        // ---------------- bow path: 1 batch row per block ----------------
        const int row  = blk - BEO_BLOCKS;
        const int lane = tid & 63;
        const int w    = tid >> 6;
        const int* srow = s + row * SEQ;

        // lane j holds token j (j<50); others hold -3 (never matches)
        int tokl = (lane < SEQ) ? srow[lane] : -3;

        int   tk[GITER];
        float mk[GITER];
        #pragma unroll
        for (int ii = 0; ii < GITER; ++ii) {
            const int i = w + 4*ii;                 // this wave's token index
            int t = (i < SEQ) ? srow[i] : -3;       // uniform addr -> s_load
            t = __builtin_amdgcn_readfirstlane(t);
            unsigned long long dup = __ballot(lane < i && tokl == t);
            mk[ii] = (t >= 0 && dup == 0ull) ? 1.0f : 0.0f;
            tk[ii] = (t < 0) ? 0 : t;
        }

        // 13 1KB row-gathers (lane l -> cols 4l..4l+3)
        float4 v[GITER];
        const float* wbase = Wbh + (size_t)lane * 4;
        #pragma unroll
        for (int ii = 0; ii < GITER; ++ii)
            v[ii] = *(const float4*)(wbase + (size_t)tk[ii] * HID);
        __builtin_amdgcn_sched_barrier(0);

        float ax = 0.f, ay = 0.f, az = 0.f, aw = 0.f;
        #pragma unroll
        for (int ii = 0; ii < GITER; ++ii) {
            ax = fmaf(mk[ii], v[ii].x, ax);
            ay = fmaf(mk[ii], v[ii].y, ay);
            az = fmaf(mk[ii], v[ii].z, az);
            aw = fmaf(mk[ii], v[ii].w, aw);
        }
        *(float4*)&sm.bow.part[w*HID + lane*4] = make_float4(ax, ay, az, aw);
        __syncthreads();
        {
            float hv = sm.bow.part[tid] + sm.bow.part[HID + tid]
                     + sm.bow.part[2*HID + tid] + sm.bow.part[3*HID + tid]
                     + bbh[tid];
            hv = hv > 0.f ? hv : 0.2f*hv;
            sm.bow.h[tid] = hv;
        }
        __syncthreads();

        // embd head: 64 outs, 4 partials each (float4 form)
        {
            const int jj = tid & 63, p = tid >> 6;
            const float4* h4 = (const float4*)sm.bow.h;
            float ps = 0.f;
            #pragma unroll 4
            for (int k4 = 0; k4 < 16; ++k4) {
                float4 hv = h4[p*16 + k4];
                const float* wp = Wbe + (size_t)(p*64 + 4*k4)*NE + jj;
                ps = fmaf(hv.x, wp[0],    ps);
                ps = fmaf(hv.y, wp[NE],   ps);
                ps = fmaf(hv.z, wp[2*NE], ps);
                ps = fmaf(hv.w, wp[3*NE], ps);
            }
            sm.bow.part[tid] = ps;
        }
        __syncthreads();
        // pred partials: 5 outs x 8 partials (threads 0..39), reads h only
        float pp = 0.f;
        if (tid < 8*NP) {
            const int p = tid / NP, jj = tid % NP;
            #pragma unroll 8
            for (int kk = 0; kk < 32; ++kk) {
                int k = p*32 + kk;
                pp = fmaf(sm.bow.h[k], Wbp[k*NP + jj], pp);
            }
        }
        // embd reduce (part holds embd partials here)
        if (tid < NE) {
            float e = sm.bow.part[tid] + sm.bow.part[tid+64]
                    + sm.bow.part[tid+128] + sm.bow.part[tid+192] + bbe[tid];
            out[OFF_BOW_E + (size_t)row*NE + tid] = e;
        }
        __syncthreads();
        if (tid < 8*NP) sm.bow.part[tid] = pp;
        __syncthreads();
        if (tid < NP) {
            float sp = bbp[tid];
            #pragma unroll
            for (int q = 0; q < 8; ++q) sp += sm.bow.part[q*NP + tid];
            out[OFF_BOW_P + (size_t)row*NP + tid] = sp;
        }
    }
}

extern "C" void kernel_launch(void* const* d_in, const int* in_sizes, int n_in,
                              void* d_out, int out_size, void* d_ws, size_t ws_size,
                              hipStream_t stream) {
    const int*   s   = (const int*)  d_in[0];
    const float* x   = (const float*)d_in[1];
    const float* Wbh = (const float*)d_in[2];
    const float* bbh = (const float*)d_in[3];
    const float* Wbp = (const float*)d_in[4];
    const float* bbp = (const float*)d_in[5];
    const float* Wbe = (const float*)d_in[6];
    const float* bbe = (const float*)d_in[7];
    const float* Weh = (const float*)d_in[8];
    const float* beh = (const float*)d_in[9];
    const float* Wep = (const float*)d_in[10];
    const float* bep = (const float*)d_in[11];
    const float* Wee = (const float*)d_in[12];
    const float* bee = (const float*)d_in[13];

    fused_kernel<<<dim3(NBLK), dim3(256), 0, stream>>>(
        s, x, Wbh, bbh, Wbp, bbp, Wbe, bbe,
        Weh, beh, Wep, bep, Wee, bee, (float*)d_out);
}